// Round 9
// baseline (85.737 us; speedup 1.0000x reference)
//
#include <hip/hip_runtime.h>

// QuantLinearMarlin: out[16,8192] = x[16,8192] @ dequant(qweight[1024,8192], scales[64,8192]) + bias
//   dequant: w[k,n] = (nibble(qweight[k/8,n], k%8) - 8) * scales[k/128, n]
// Harness dtypes: fp16 reference canonicalized to f32 -> x/scales/bias/out are float*.
//
// Round 9: R8 = 83.77 us (prediction matched). Kernel chain ~7.8 us vs ~6.8-7 floor
// (main ~5.8 vs 5.3 qweight-read floor; prologue ~2 us). This round: shrink the
// prologue's launch ramp - bias-init vectorized float4 x2 (64 blocks, was 512) and
// prepack at 4 S-steps/block (64 blocks, was 64 block-equivalents at 576 total).
// Prologue: 576 -> 128 blocks. Main kernel untouched (verified winner R7/R8).
// Decision rule: if neutral (>=83.5), prologue is at dispatch-latency floor ->
// declare roofline.

#define K_DIM 8192
#define N_DIM 8192

typedef _Float16 h2 __attribute__((ext_vector_type(2)));
typedef _Float16 h8 __attribute__((ext_vector_type(8)));
typedef float f32x4 __attribute__((ext_vector_type(4)));
union H8U { unsigned u[4]; h8 h; };

__device__ __forceinline__ unsigned pkrtz_u(float a, float b) {
  return __builtin_bit_cast(unsigned, __builtin_amdgcn_cvt_pkrtz(a, b));
}
__device__ __forceinline__ h2 dup_h2(float v) {
  return __builtin_bit_cast(h2, pkrtz_u(v, v));
}

// Fused prologue, 128 blocks x 256 threads:
//   blocks 0..63  : out = bias broadcast (float4 x2 per thread; 64*256*8 = 131072)
//   blocks 64..127: prepack x -> lane-linear fp16 A-fragments,
//     xpk[S*256 + L*4 + p] = pack(x[m][32S+8q+p], x[m][32S+8q+p+4]), q=L>>4, m=L&15
__global__ void prologue_kernel(const float* __restrict__ bias,
                                const float* __restrict__ x,
                                float* __restrict__ out,
                                unsigned* __restrict__ xpk) {
  const int b = blockIdx.x, t = threadIdx.x;
  if (b < 64) {
    // i = b*2048 + t*8 -> col = i & 8191 = (b&3)*2048 + t*8 (rows repeat bias)
    int i = (b << 11) + (t << 3);
    const float4* bp = (const float4*)(bias + (i & (N_DIM - 1)));
    float4* op = (float4*)(out + i);
    op[0] = bp[0];
    op[1] = bp[1];
  } else {
    int S = ((b - 64) << 2) + (t >> 6);  // k-step 0..255
    int L = t & 63;                      // lane
    int q = L >> 4, m = L & 15;
    const float* xp = x + (size_t)m * K_DIM + 32 * S + 8 * q;
    float4 lo = *(const float4*)xp;
    float4 hi = *(const float4*)(xp + 4);
    unsigned* o = xpk + S * 256 + L * 4;
    o[0] = pkrtz_u(lo.x, hi.x);
    o[1] = pkrtz_u(lo.y, hi.y);
    o[2] = pkrtz_u(lo.z, hi.z);
    o[3] = pkrtz_u(lo.w, hi.w);
  }
}

__global__ __launch_bounds__(512, 8) void qlin_main(
    const unsigned* __restrict__ xpk,  // [256][64][4] packed A fragments
    const int* __restrict__ qw,        // [1024][8192]
    const float* __restrict__ scales,  // [64][8192]
    float* __restrict__ out) {         // [16][8192], pre-filled with bias
  __shared__ float red[8][512];

  const int tid = threadIdx.x;
  const int wv = tid >> 6;            // 0..7
  const int lane = tid & 63;
  const int c = lane & 15;            // B col / C col (and A row m in fragments)
  const int quad = lane >> 4;         // 0..3
  const int ntb = blockIdx.x & 255;   // N-tile
  const int ksb = blockIdx.x >> 8;    // K-split 0..3
  const int nb = ntb * 32;
  const int S0 = ksb * 64 + wv * 8;   // this wave's global k-step base (8 steps)

  // ---- prefetch: all 8 qweight int2 + both scale float2, in flight together ----
  const int* qp = qw + (size_t)(4 * S0 + quad) * N_DIM + nb + 2 * c;
  int2 qv[8];
#pragma unroll
  for (int s = 0; s < 8; ++s) qv[s] = *(const int2*)(qp + (size_t)(4 * s) * N_DIM);
  const float* sp = scales + (size_t)(S0 >> 2) * N_DIM + nb + 2 * c;
  float2 svA = *(const float2*)sp;            // groups: steps 0..3
  float2 svB = *(const float2*)(sp + N_DIM);  // steps 4..7

  // A: lane-linear dwordx4, rolling double buffer
  const unsigned* ap = xpk + (size_t)S0 * 256 + lane * 4;
  uint4 av[2];
  av[0] = *(const uint4*)ap;

  const h2 koff = __builtin_bit_cast(h2, 0x64086408u);  // (1032.0h, 1032.0h)
  h2 s0A = dup_h2(svA.x), s1A = dup_h2(svA.y);
  h2 s0B = dup_h2(svB.x), s1B = dup_h2(svB.y);

  f32x4 acc0 = {0.f, 0.f, 0.f, 0.f};  // cols nb + 2c
  f32x4 acc1 = {0.f, 0.f, 0.f, 0.f};  // cols nb + 2c + 1

#pragma unroll
  for (int s = 0; s < 8; ++s) {
    if (s < 7) av[(s + 1) & 1] = *(const uint4*)(ap + (s + 1) * 256);
    h2 s0 = (s < 4) ? s0A : s0B;  // resolved at compile time under full unroll
    h2 s1 = (s < 4) ? s1A : s1B;
    uint4 u = av[s & 1];
    H8U a;
    a.u[0] = u.x; a.u[1] = u.y; a.u[2] = u.z; a.u[3] = u.w;
    unsigned qa = (unsigned)qv[s].x, qb = (unsigned)qv[s].y;
    H8U b0, b1;
#pragma unroll
    for (int p = 0; p < 4; ++p) {
      unsigned t0 = ((qa >> (4 * p)) & 0x000F000Fu) | 0x64006400u;
      unsigned t1 = ((qb >> (4 * p)) & 0x000F000Fu) | 0x64006400u;
      h2 w0 = (__builtin_bit_cast(h2, t0) - koff) * s0;  // (nib-8) exact, then *s
      h2 w1 = (__builtin_bit_cast(h2, t1) - koff) * s1;
      b0.u[p] = __builtin_bit_cast(unsigned, w0);
      b1.u[p] = __builtin_bit_cast(unsigned, w1);
    }
    acc0 = __builtin_amdgcn_mfma_f32_16x16x32_f16(a.h, b0.h, acc0, 0, 0, 0);
    acc1 = __builtin_amdgcn_mfma_f32_16x16x32_f16(a.h, b1.h, acc1, 0, 0, 0);
  }

  // C/D layout: col = lane&15 (=c), row m = quad*4 + reg
#pragma unroll
  for (int r = 0; r < 4; ++r) {
    int m = quad * 4 + r;
    red[wv][m * 32 + 2 * c] = acc0[r];
    red[wv][m * 32 + 2 * c + 1] = acc1[r];
  }
  __syncthreads();

  // 512 threads: one (m, j) output each; sum 8 in-block partials, one atomic
  {
    int j = tid & 31, m = tid >> 5;
    float v = 0.f;
#pragma unroll
    for (int w = 0; w < 8; ++w) v += red[w][tid];
    unsafeAtomicAdd(&out[(size_t)m * N_DIM + nb + j], v);
  }
}

extern "C" void kernel_launch(void* const* d_in, const int* in_sizes, int n_in,
                              void* d_out, int out_size, void* d_ws, size_t ws_size,
                              hipStream_t stream) {
  const float* x      = (const float*)d_in[0];  // [16,8192] f32
  const int* qw       = (const int*)d_in[1];    // [1024,8192] i32
  const float* scales = (const float*)d_in[2];  // [64,8192] f32
  const float* bias   = (const float*)d_in[3];  // [8192] f32
  float* out          = (float*)d_out;          // [16,8192] f32
  unsigned* xpk       = (unsigned*)d_ws;        // 256 KB of the workspace

  prologue_kernel<<<128, 256, 0, stream>>>(bias, x, out, xpk);
  qlin_main<<<1024, 512, 0, stream>>>(xpk, qw, scales, out);
}

// Round 10
// 83.682 us; speedup vs baseline: 1.0246x; 1.0246x over previous
//
#include <hip/hip_runtime.h>

// QuantLinearMarlin: out[16,8192] = x[16,8192] @ dequant(qweight[1024,8192], scales[64,8192]) + bias
//   dequant: w[k,n] = (nibble(qweight[k/8,n], k%8) - 8) * scales[k/128, n]
// Harness dtypes: fp16 reference canonicalized to f32 -> x/scales/bias/out are float*.
//
// FINAL (revert to R8, best measured = 83.77 us):
//  - prologue (576 blocks): bias-init into out (atomic accumulation base) + prepack
//    x into lane-linear fp16 A-fragments in d_ws.
//  - main (1024 x 512, 32 waves/CU): per-wave full prefetch (8x int2 qweight +
//    scales), Marlin fp16 nibble dequant, mfma_f32_16x16x32_f16, 4-way K-split
//    reduced via LDS + unsafeAtomicAdd.
// Ceiling accounting (R4/R6 probes + R7-R9 counter-validated): fixed harness
// ~76 us; main ~5.8 us vs 5.3 us qweight(32MB)-read floor; prologue ~2 us ~=
// dispatch latency. R9's smaller prologue regressed -> reverted.

#define K_DIM 8192
#define N_DIM 8192

typedef _Float16 h2 __attribute__((ext_vector_type(2)));
typedef _Float16 h8 __attribute__((ext_vector_type(8)));
typedef float f32x4 __attribute__((ext_vector_type(4)));
union H8U { unsigned u[4]; h8 h; };

__device__ __forceinline__ unsigned pkrtz_u(float a, float b) {
  return __builtin_bit_cast(unsigned, __builtin_amdgcn_cvt_pkrtz(a, b));
}
__device__ __forceinline__ h2 dup_h2(float v) {
  return __builtin_bit_cast(h2, pkrtz_u(v, v));
}

// Fused prologue: blocks 0..511 -> out = bias (atomic accumulation base);
// blocks 512..575 -> prepack x into lane-linear fp16 A-fragments:
//   xpk[S*256 + L*4 + p] = pack(x[m][32S+8q+p], x[m][32S+8q+p+4]), q=L>>4, m=L&15
__global__ void prologue_kernel(const float* __restrict__ bias,
                                const float* __restrict__ x,
                                float* __restrict__ out,
                                unsigned* __restrict__ xpk) {
  const int b = blockIdx.x, t = threadIdx.x;
  if (b < 512) {
    int i = b * 256 + t;  // 512*256 = 131072 = 16*8192
    out[i] = bias[i & (N_DIM - 1)];
  } else {
    int S = (b - 512) * 4 + (t >> 6);  // k-step 0..255
    int L = t & 63;                    // lane
    int q = L >> 4, m = L & 15;
    const float* xp = x + (size_t)m * K_DIM + 32 * S + 8 * q;
    float4 lo = *(const float4*)xp;
    float4 hi = *(const float4*)(xp + 4);
    unsigned* o = xpk + S * 256 + L * 4;
    o[0] = pkrtz_u(lo.x, hi.x);
    o[1] = pkrtz_u(lo.y, hi.y);
    o[2] = pkrtz_u(lo.z, hi.z);
    o[3] = pkrtz_u(lo.w, hi.w);
  }
}

__global__ __launch_bounds__(512, 8) void qlin_main(
    const unsigned* __restrict__ xpk,  // [256][64][4] packed A fragments
    const int* __restrict__ qw,        // [1024][8192]
    const float* __restrict__ scales,  // [64][8192]
    float* __restrict__ out) {         // [16][8192], pre-filled with bias
  __shared__ float red[8][512];

  const int tid = threadIdx.x;
  const int wv = tid >> 6;            // 0..7
  const int lane = tid & 63;
  const int c = lane & 15;            // B col / C col (and A row m in fragments)
  const int quad = lane >> 4;         // 0..3
  const int ntb = blockIdx.x & 255;   // N-tile
  const int ksb = blockIdx.x >> 8;    // K-split 0..3
  const int nb = ntb * 32;
  const int S0 = ksb * 64 + wv * 8;   // this wave's global k-step base (8 steps)

  // ---- prefetch: all 8 qweight int2 + both scale float2, in flight together ----
  const int* qp = qw + (size_t)(4 * S0 + quad) * N_DIM + nb + 2 * c;
  int2 qv[8];
#pragma unroll
  for (int s = 0; s < 8; ++s) qv[s] = *(const int2*)(qp + (size_t)(4 * s) * N_DIM);
  const float* sp = scales + (size_t)(S0 >> 2) * N_DIM + nb + 2 * c;
  float2 svA = *(const float2*)sp;            // groups: steps 0..3
  float2 svB = *(const float2*)(sp + N_DIM);  // steps 4..7

  // A: lane-linear dwordx4, rolling double buffer
  const unsigned* ap = xpk + (size_t)S0 * 256 + lane * 4;
  uint4 av[2];
  av[0] = *(const uint4*)ap;

  const h2 koff = __builtin_bit_cast(h2, 0x64086408u);  // (1032.0h, 1032.0h)
  h2 s0A = dup_h2(svA.x), s1A = dup_h2(svA.y);
  h2 s0B = dup_h2(svB.x), s1B = dup_h2(svB.y);

  f32x4 acc0 = {0.f, 0.f, 0.f, 0.f};  // cols nb + 2c
  f32x4 acc1 = {0.f, 0.f, 0.f, 0.f};  // cols nb + 2c + 1

#pragma unroll
  for (int s = 0; s < 8; ++s) {
    if (s < 7) av[(s + 1) & 1] = *(const uint4*)(ap + (s + 1) * 256);
    h2 s0 = (s < 4) ? s0A : s0B;  // resolved at compile time under full unroll
    h2 s1 = (s < 4) ? s1A : s1B;
    uint4 u = av[s & 1];
    H8U a;
    a.u[0] = u.x; a.u[1] = u.y; a.u[2] = u.z; a.u[3] = u.w;
    unsigned qa = (unsigned)qv[s].x, qb = (unsigned)qv[s].y;
    H8U b0, b1;
#pragma unroll
    for (int p = 0; p < 4; ++p) {
      unsigned t0 = ((qa >> (4 * p)) & 0x000F000Fu) | 0x64006400u;
      unsigned t1 = ((qb >> (4 * p)) & 0x000F000Fu) | 0x64006400u;
      h2 w0 = (__builtin_bit_cast(h2, t0) - koff) * s0;  // (nib-8) exact, then *s
      h2 w1 = (__builtin_bit_cast(h2, t1) - koff) * s1;
      b0.u[p] = __builtin_bit_cast(unsigned, w0);
      b1.u[p] = __builtin_bit_cast(unsigned, w1);
    }
    acc0 = __builtin_amdgcn_mfma_f32_16x16x32_f16(a.h, b0.h, acc0, 0, 0, 0);
    acc1 = __builtin_amdgcn_mfma_f32_16x16x32_f16(a.h, b1.h, acc1, 0, 0, 0);
  }

  // C/D layout: col = lane&15 (=c), row m = quad*4 + reg
#pragma unroll
  for (int r = 0; r < 4; ++r) {
    int m = quad * 4 + r;
    red[wv][m * 32 + 2 * c] = acc0[r];
    red[wv][m * 32 + 2 * c + 1] = acc1[r];
  }
  __syncthreads();

  // 512 threads: one (m, j) output each; sum 8 in-block partials, one atomic
  {
    int j = tid & 31, m = tid >> 5;
    float v = 0.f;
#pragma unroll
    for (int w = 0; w < 8; ++w) v += red[w][tid];
    unsafeAtomicAdd(&out[(size_t)m * N_DIM + nb + j], v);
  }
}

extern "C" void kernel_launch(void* const* d_in, const int* in_sizes, int n_in,
                              void* d_out, int out_size, void* d_ws, size_t ws_size,
                              hipStream_t stream) {
  const float* x      = (const float*)d_in[0];  // [16,8192] f32
  const int* qw       = (const int*)d_in[1];    // [1024,8192] i32
  const float* scales = (const float*)d_in[2];  // [64,8192] f32
  const float* bias   = (const float*)d_in[3];  // [8192] f32
  float* out          = (float*)d_out;          // [16,8192] f32
  unsigned* xpk       = (unsigned*)d_ws;        // 256 KB of the workspace

  prologue_kernel<<<576, 256, 0, stream>>>(bias, x, out, xpk);
  qlin_main<<<1024, 512, 0, stream>>>(xpk, qw, scales, out);
}